// Round 1
// baseline (3994.161 us; speedup 1.0000x reference)
//
#include <hip/hip_runtime.h>
#include <math.h>

#define NS 48
#define NC 64

// Materialized conv kernel: k[tap(125)][in(64)][out(64)], tap = (tx*5+ty)*5+tz
__device__ float g_K[125 * 64 * 64];

__global__ __launch_bounds__(256) void build_kernel(
    const float* __restrict__ w000, const float* __restrict__ w011,
    const float* __restrict__ w101, const float* __restrict__ w110,
    const float* __restrict__ sc0,  const float* __restrict__ sc1) {
  const int tap = blockIdx.x;  // 0..124
  const int tz = tap % 5, ty = (tap / 5) % 5, tx = tap / 25;
  const float cx = (float)(tx - 2), cy = (float)(ty - 2), cz = (float)(tz - 2);
  const float norm = sqrtf(cx * cx + cy * cy + cz * cz);
  const float inv = (norm > 0.f) ? (1.f / norm) : 0.f;
  const float SQ3 = 1.7320508075688772f;
  const float sh[3] = {SQ3 * cx * inv, SQ3 * cy * inv, SQ3 * cz * inv};
  float emb[4];
#pragma unroll
  for (int b = 0; b < 4; ++b) {
    const float v = 0.5f * (float)(b + 1);
    const float d = (norm - v) * 2.0f;  // step = 0.5
    emb[b] = (fabsf(d) < 1.f) ? 1.14136f * expf(2.f - 1.f / (1.f - d * d)) : 0.f;
  }
  const bool center = (tap == 62);  // (2,2,2)
  float* kt = g_K + tap * 4096;
  const float INV_NLAT = 1.0f / 125.0f;
  const float INV_SQ3 = 0.57735026918962576f;
  for (int e = threadIdx.x; e < 4096; e += blockDim.x) {
    const int r = e >> 6, c = e & 63;  // r = input ch, c = output ch
    float val = 0.f;
    if (center) {
      // self-connection (FunctionalLinear, std 1/sqrt(16) = 0.25)
      if (r < 16 && c < 16) {
        val = sc0[r * 16 + c] * 0.25f;
      } else if (r >= 16 && c >= 16) {
        const int u = (r - 16) / 3, i = (r - 16) % 3;
        const int w = (c - 16) / 3, kc = (c - 16) % 3;
        val = (i == kc) ? sc1[u * 16 + w] * 0.25f : 0.f;
      }
    } else {
      if (r < 16 && c < 16) {
        // 0e x 0e -> 0e
        float a = 0.f;
#pragma unroll
        for (int b = 0; b < 4; ++b) a += emb[b] * w000[(b * 16 + r) * 16 + c];
        val = a * INV_NLAT;
      } else if (r < 16) {
        // 0e x 1o -> 1o : col = 16 + w*3 + kc, value r011[u,w]*sh1[kc]
        const int w = (c - 16) / 3, kc = (c - 16) % 3;
        float a = 0.f;
#pragma unroll
        for (int b = 0; b < 4; ++b) a += emb[b] * w011[(b * 16 + r) * 16 + w];
        val = a * INV_NLAT * sh[kc];
      } else if (c < 16) {
        // 1o x 1o -> 0e : row = 16 + u*3 + i, value r110[u,w]*sh1[i]/sqrt(3)
        const int u = (r - 16) / 3, i = (r - 16) % 3;
        float a = 0.f;
#pragma unroll
        for (int b = 0; b < 4; ++b) a += emb[b] * w110[(b * 16 + u) * 16 + c];
        val = a * INV_NLAT * sh[i] * INV_SQ3;
      } else {
        // 1o x 0e -> 1o : value r101[u,w] * delta(i,kc)
        const int u = (r - 16) / 3, i = (r - 16) % 3;
        const int w = (c - 16) / 3, kc = (c - 16) % 3;
        if (i == kc) {
          float a = 0.f;
#pragma unroll
          for (int b = 0; b < 4; ++b) a += emb[b] * w101[(b * 16 + u) * 16 + w];
          val = a * INV_NLAT;
        }
      }
    }
    kt[e] = val;
  }
}

// One block per (X, Y, n). Block computes out[n, X, Y, 0..47, 0..63].
// Thread t: o in {4*(t&15) .. +3}, z in {3*(t>>4) .. +2}.
__global__ __launch_bounds__(256) void conv_kernel(
    const float* __restrict__ x, float* __restrict__ out) {
  __shared__ float xs[64][53];  // [in_ch][z'(-2..49)], padded stride 53
  const int X = blockIdx.x, Y = blockIdx.y, n = blockIdx.z;
  const int t = threadIdx.x;
  const int og = t & 15;   // o base = og*4
  const int zg = t >> 4;   // z base = zg*3
  const int zb = zg * 3;

  float4 acc[3];
#pragma unroll
  for (int j = 0; j < 3; ++j) acc[j] = make_float4(0.f, 0.f, 0.f, 0.f);

  for (int dx = 0; dx < 5; ++dx) {
    const int xx = X + dx - 2;
    for (int dy = 0; dy < 5; ++dy) {
      const int yy = Y + dy - 2;
      const bool valid = ((unsigned)xx < 48u) && ((unsigned)yy < 48u);
      __syncthreads();
      // stage x[n, xx, yy, z'-2..z'+49, :] transposed into LDS (zeros at pads)
      const long long rowbase =
          (((long long)n * NS + xx) * NS + yy) * (long long)(NS * NC);
#pragma unroll
      for (int idx = t; idx < 52 * 64; idx += 256) {
        const int zi = idx >> 6, i = idx & 63;
        const int zsrc = zi - 2;
        float v = 0.f;
        if (valid && (unsigned)zsrc < 48u) v = x[rowbase + zsrc * NC + i];
        xs[i][zi] = v;
      }
      __syncthreads();

      const float* kp = g_K + (((size_t)(dx * 5 + dy) * 5) << 12) + og * 4;
#pragma unroll 2
      for (int i = 0; i < 64; ++i) {
        float xv[7];
#pragma unroll
        for (int q = 0; q < 7; ++q) xv[q] = xs[i][zb + q];
#pragma unroll
        for (int dz = 0; dz < 5; ++dz) {
          const float4 kk = *(const float4*)(kp + ((size_t)dz << 12) + i * 64);
          acc[0].x += xv[dz + 0] * kk.x;
          acc[0].y += xv[dz + 0] * kk.y;
          acc[0].z += xv[dz + 0] * kk.z;
          acc[0].w += xv[dz + 0] * kk.w;
          acc[1].x += xv[dz + 1] * kk.x;
          acc[1].y += xv[dz + 1] * kk.y;
          acc[1].z += xv[dz + 1] * kk.z;
          acc[1].w += xv[dz + 1] * kk.w;
          acc[2].x += xv[dz + 2] * kk.x;
          acc[2].y += xv[dz + 2] * kk.y;
          acc[2].z += xv[dz + 2] * kk.z;
          acc[2].w += xv[dz + 2] * kk.w;
        }
      }
    }
  }

  float* op = out + (((size_t)n * NS + X) * NS + Y) * (size_t)(NS * NC);
#pragma unroll
  for (int j = 0; j < 3; ++j) {
    *(float4*)(op + (size_t)(zb + j) * NC + og * 4) = acc[j];
  }
}

extern "C" void kernel_launch(void* const* d_in, const int* in_sizes, int n_in,
                              void* d_out, int out_size, void* d_ws, size_t ws_size,
                              hipStream_t stream) {
  const float* x    = (const float*)d_in[0];
  const float* w000 = (const float*)d_in[1];
  const float* w011 = (const float*)d_in[2];
  const float* w101 = (const float*)d_in[3];
  const float* w110 = (const float*)d_in[4];
  const float* sc0  = (const float*)d_in[5];
  const float* sc1  = (const float*)d_in[6];
  float* out = (float*)d_out;

  build_kernel<<<125, 256, 0, stream>>>(w000, w011, w101, w110, sc0, sc1);
  dim3 grid(NS, NS, 2);
  conv_kernel<<<grid, 256, 0, stream>>>(x, out);
}

// Round 2
// 328.994 us; speedup vs baseline: 12.1405x; 12.1405x over previous
//
#include <hip/hip_runtime.h>
#include <math.h>

typedef __attribute__((ext_vector_type(8))) short short8;
typedef __attribute__((ext_vector_type(4))) float float4v;

#define NS 48
#define PS 52
#define NC 64

// padded bf16 input: [n][xx 0..51][yy 0..51][zz 0..51][i], borders zero
__device__ __align__(16) unsigned short g_xb[(size_t)2 * PS * PS * PS * NC];
// kernel in MFMA B-fragment layout: [tap 125][ik 2][of 4][lane 64][j 8]
__device__ __align__(16) unsigned short g_kb[125 * 2 * 4 * 64 * 8];

__device__ __forceinline__ unsigned short bf16r(float f) {
  unsigned u = __builtin_bit_cast(unsigned, f);
  u = (u + 0x7FFFu + ((u >> 16) & 1u)) >> 16;
  return (unsigned short)u;
}

__global__ __launch_bounds__(256) void pad_cast(const float* __restrict__ x) {
  const int bx = blockIdx.x;  // xx*52+yy
  const int n = blockIdx.y;
  const int xx = bx / 52, yy = bx % 52;
  const bool inxy = (xx >= 2) && (xx < 50) && (yy >= 2) && (yy < 50);
  unsigned short* dst = g_xb + (((size_t)n * 52 + xx) * 52 + yy) * 3328;
  const float* src = x + ((((size_t)n * 48 + (xx - 2)) * 48 + (yy - 2)) * 48) * 64;
#pragma unroll 1
  for (int tt = threadIdx.x; tt < 832; tt += 256) {
    const int zz = tt >> 4;
    const int i4 = (tt & 15) * 4;
    ushort4 v = make_ushort4(0, 0, 0, 0);
    if (inxy && zz >= 2 && zz < 50) {
      const float4 f = *(const float4*)(src + (size_t)(zz - 2) * 64 + i4);
      v.x = bf16r(f.x); v.y = bf16r(f.y); v.z = bf16r(f.z); v.w = bf16r(f.w);
    }
    *(ushort4*)(dst + (size_t)zz * 64 + i4) = v;
  }
}

__global__ __launch_bounds__(256) void build_kb(
    const float* __restrict__ w000, const float* __restrict__ w011,
    const float* __restrict__ w101, const float* __restrict__ w110,
    const float* __restrict__ sc0,  const float* __restrict__ sc1) {
  const int tap = blockIdx.x;  // 0..124
  const int tz = tap % 5, ty = (tap / 5) % 5, tx = tap / 25;
  const float cx = (float)(tx - 2), cy = (float)(ty - 2), cz = (float)(tz - 2);
  const float norm = sqrtf(cx * cx + cy * cy + cz * cz);
  const float inv = (norm > 0.f) ? (1.f / norm) : 0.f;
  const float SQ3 = 1.7320508075688772f;
  const float sh[3] = {SQ3 * cx * inv, SQ3 * cy * inv, SQ3 * cz * inv};
  float emb[4];
#pragma unroll
  for (int b = 0; b < 4; ++b) {
    const float v = 0.5f * (float)(b + 1);
    const float d = (norm - v) * 2.0f;
    emb[b] = (fabsf(d) < 1.f) ? 1.14136f * expf(2.f - 1.f / (1.f - d * d)) : 0.f;
  }
  const bool center = (tap == 62);
  const float INV_NLAT = 1.0f / 125.0f;
  const float INV_SQ3 = 0.57735026918962576f;
  for (int e = threadIdx.x; e < 4096; e += blockDim.x) {
    const int r = e >> 6, c = e & 63;  // r = input ch, c = output ch
    float val = 0.f;
    if (center) {
      if (r < 16 && c < 16) {
        val = sc0[r * 16 + c] * 0.25f;
      } else if (r >= 16 && c >= 16) {
        const int u = (r - 16) / 3, i = (r - 16) % 3;
        const int w = (c - 16) / 3, kc = (c - 16) % 3;
        val = (i == kc) ? sc1[u * 16 + w] * 0.25f : 0.f;
      }
    } else {
      if (r < 16 && c < 16) {
        float a = 0.f;
#pragma unroll
        for (int b = 0; b < 4; ++b) a += emb[b] * w000[(b * 16 + r) * 16 + c];
        val = a * INV_NLAT;
      } else if (r < 16) {
        const int w = (c - 16) / 3, kc = (c - 16) % 3;
        float a = 0.f;
#pragma unroll
        for (int b = 0; b < 4; ++b) a += emb[b] * w011[(b * 16 + r) * 16 + w];
        val = a * INV_NLAT * sh[kc];
      } else if (c < 16) {
        const int u = (r - 16) / 3, i = (r - 16) % 3;
        float a = 0.f;
#pragma unroll
        for (int b = 0; b < 4; ++b) a += emb[b] * w110[(b * 16 + u) * 16 + c];
        val = a * INV_NLAT * sh[i] * INV_SQ3;
      } else {
        const int u = (r - 16) / 3, i = (r - 16) % 3;
        const int w = (c - 16) / 3, kc = (c - 16) % 3;
        if (i == kc) {
          float a = 0.f;
#pragma unroll
          for (int b = 0; b < 4; ++b) a += emb[b] * w101[(b * 16 + u) * 16 + w];
          val = a * INV_NLAT;
        }
      }
    }
    // permute into B-fragment layout: B[k = i - ik*32][n = o] per (tap, ik, of)
    const int ik = r >> 5;
    const int lane = ((r >> 3) & 3) * 16 + (c & 15);
    const int of = c >> 4;
    const int j = r & 7;
    g_kb[((size_t)((tap * 2 + ik) * 4 + of) * 64 + lane) * 8 + j] = bf16r(val);
  }
}

// Block: (X, y-group of 4, n). Wave w = y row (y0+w). Out tile: 4y x 48z x 64o.
__global__ __launch_bounds__(256, 3) void conv_mfma(float* __restrict__ out) {
  __shared__ __align__(16) char xs[8 * 52 * 128];  // 8y x 52z x 64i bf16 = 53248 B
  const int t = threadIdx.x;
  const int l = t & 63;
  const int wid = t >> 6;      // wave id = local y
  const int m = l & 15;        // MFMA row/col-within-frag
  const int kq = l >> 4;       // k-quad 0..3
  const int X = blockIdx.x;
  const int y0 = blockIdx.y << 2;
  const int n = blockIdx.z;

  float4v acc[3][4];
  const float4v zero4 = {0.f, 0.f, 0.f, 0.f};
#pragma unroll
  for (int zt = 0; zt < 3; ++zt)
#pragma unroll
    for (int of = 0; of < 4; ++of) acc[zt][of] = zero4;

#pragma unroll 1
  for (int dx = 0; dx < 5; ++dx) {
    __syncthreads();
    {
      // stage 8y x 52z slab for xx = X+dx-2 (padded idx X+dx), yy = y0..y0+7
      const unsigned short* gx =
          g_xb + ((size_t)n * PS + (X + dx)) * 173056 + (size_t)y0 * 3328;
#pragma unroll
      for (int s = 0; s < 13; ++s) {
        const int c_all = t + 256 * s;       // 16B-chunk id, 0..3327
        const int jy = c_all / 416;          // 416 chunks per y row
        const int c = c_all - jy * 416;
        const int zz = c >> 3, p = c & 7;
        const int row = jy * 52 + zz;
        const int sc = p ^ (row & 7);        // pre-swizzled source chunk
        const unsigned short* g = gx + jy * 3328 + zz * 64 + sc * 8;
        char* ldsd = xs + (size_t)(wid * 64 + s * 256) * 16;  // wave-uniform base
        __builtin_amdgcn_global_load_lds(
            (const __attribute__((address_space(1))) unsigned*)g,
            (__attribute__((address_space(3))) unsigned*)ldsd, 16, 0, 0);
      }
    }
    __syncthreads();

#pragma unroll 1
    for (int dy = 0; dy < 5; ++dy) {
      const int rb0 = (wid + dy) * 52 + m;   // slab row base (+ zt*16 + dz)
      const int tap8 = ((dx * 5 + dy) * 5) * 8;
#pragma unroll
      for (int dz = 0; dz < 5; ++dz) {
#pragma unroll
        for (int ik = 0; ik < 2; ++ik) {
          const unsigned short* kbp =
              g_kb + (size_t)(tap8 + dz * 8 + ik * 4) * 512 + l * 8;
          const short8 b0 = *(const short8*)(kbp);
          const short8 b1 = *(const short8*)(kbp + 512);
          const short8 b2 = *(const short8*)(kbp + 1024);
          const short8 b3 = *(const short8*)(kbp + 1536);
          short8 a[3];
#pragma unroll
          for (int zt = 0; zt < 3; ++zt) {
            const int row = rb0 + zt * 16 + dz;
            int byte = row * 128 + (ik * 4 + kq) * 16;
            byte ^= (row & 7) << 4;          // XOR swizzle (matches stage)
            a[zt] = *(const short8*)(xs + byte);
          }
#pragma unroll
          for (int zt = 0; zt < 3; ++zt) {
            acc[zt][0] = __builtin_amdgcn_mfma_f32_16x16x32_bf16(a[zt], b0, acc[zt][0], 0, 0, 0);
            acc[zt][1] = __builtin_amdgcn_mfma_f32_16x16x32_bf16(a[zt], b1, acc[zt][1], 0, 0, 0);
            acc[zt][2] = __builtin_amdgcn_mfma_f32_16x16x32_bf16(a[zt], b2, acc[zt][2], 0, 0, 0);
            acc[zt][3] = __builtin_amdgcn_mfma_f32_16x16x32_bf16(a[zt], b3, acc[zt][3], 0, 0, 0);
          }
        }
      }
    }
  }

  // C/D layout: col(o) = lane&15, row(z) = (lane>>4)*4 + r   [m89]
  float* op = out + ((((size_t)n * NS + X) * NS + (y0 + wid)) * NS) * NC;
#pragma unroll
  for (int zt = 0; zt < 3; ++zt) {
#pragma unroll
    for (int of = 0; of < 4; ++of) {
#pragma unroll
      for (int r = 0; r < 4; ++r) {
        const int z = zt * 16 + kq * 4 + r;
        const int o = of * 16 + m;
        op[(size_t)z * NC + o] = acc[zt][of][r];
      }
    }
  }
}

extern "C" void kernel_launch(void* const* d_in, const int* in_sizes, int n_in,
                              void* d_out, int out_size, void* d_ws, size_t ws_size,
                              hipStream_t stream) {
  const float* x    = (const float*)d_in[0];
  const float* w000 = (const float*)d_in[1];
  const float* w011 = (const float*)d_in[2];
  const float* w101 = (const float*)d_in[3];
  const float* w110 = (const float*)d_in[4];
  const float* sc0  = (const float*)d_in[5];
  const float* sc1  = (const float*)d_in[6];
  float* out = (float*)d_out;

  pad_cast<<<dim3(52 * 52, 2), 256, 0, stream>>>(x);
  build_kb<<<125, 256, 0, stream>>>(w000, w011, w101, w110, sc0, sc1);
  conv_mfma<<<dim3(48, 12, 2), 256, 0, stream>>>(out);
}

// Round 3
// 290.365 us; speedup vs baseline: 13.7557x; 1.1330x over previous
//
#include <hip/hip_runtime.h>
#include <math.h>

typedef __attribute__((ext_vector_type(8))) short short8;
typedef __attribute__((ext_vector_type(4))) float float4v;

#define NS 48
#define PS 52
#define NC 64

// padded bf16 input: [n][xx 0..51][yy 0..51][zz 0..51][i], borders zero
__device__ __align__(16) unsigned short g_xb[(size_t)2 * PS * PS * PS * NC];
// kernel in MFMA B-fragment layout: [tap 125][ik 2][of 4][lane 64][j 8]
__device__ __align__(16) unsigned short g_kb[125 * 2 * 4 * 64 * 8];

__device__ __forceinline__ unsigned short bf16r(float f) {
  unsigned u = __builtin_bit_cast(unsigned, f);
  u = (u + 0x7FFFu + ((u >> 16) & 1u)) >> 16;
  return (unsigned short)u;
}

__global__ __launch_bounds__(256) void pad_cast(const float* __restrict__ x) {
  const int bx = blockIdx.x;  // xx*52+yy
  const int n = blockIdx.y;
  const int xx = bx / 52, yy = bx % 52;
  const bool inxy = (xx >= 2) && (xx < 50) && (yy >= 2) && (yy < 50);
  unsigned short* dst = g_xb + (((size_t)n * 52 + xx) * 52 + yy) * 3328;
  const float* src = x + ((((size_t)n * 48 + (xx - 2)) * 48 + (yy - 2)) * 48) * 64;
#pragma unroll 1
  for (int tt = threadIdx.x; tt < 832; tt += 256) {
    const int zz = tt >> 4;
    const int i4 = (tt & 15) * 4;
    ushort4 v = make_ushort4(0, 0, 0, 0);
    if (inxy && zz >= 2 && zz < 50) {
      const float4 f = *(const float4*)(src + (size_t)(zz - 2) * 64 + i4);
      v.x = bf16r(f.x); v.y = bf16r(f.y); v.z = bf16r(f.z); v.w = bf16r(f.w);
    }
    *(ushort4*)(dst + (size_t)zz * 64 + i4) = v;
  }
}

__global__ __launch_bounds__(256) void build_kb(
    const float* __restrict__ w000, const float* __restrict__ w011,
    const float* __restrict__ w101, const float* __restrict__ w110,
    const float* __restrict__ sc0,  const float* __restrict__ sc1) {
  const int tap = blockIdx.x;  // 0..124
  const int tz = tap % 5, ty = (tap / 5) % 5, tx = tap / 25;
  const float cx = (float)(tx - 2), cy = (float)(ty - 2), cz = (float)(tz - 2);
  const float norm = sqrtf(cx * cx + cy * cy + cz * cz);
  const float inv = (norm > 0.f) ? (1.f / norm) : 0.f;
  const float SQ3 = 1.7320508075688772f;
  const float sh[3] = {SQ3 * cx * inv, SQ3 * cy * inv, SQ3 * cz * inv};
  float emb[4];
#pragma unroll
  for (int b = 0; b < 4; ++b) {
    const float v = 0.5f * (float)(b + 1);
    const float d = (norm - v) * 2.0f;
    emb[b] = (fabsf(d) < 1.f) ? 1.14136f * expf(2.f - 1.f / (1.f - d * d)) : 0.f;
  }
  const bool center = (tap == 62);
  const float INV_NLAT = 1.0f / 125.0f;
  const float INV_SQ3 = 0.57735026918962576f;
  for (int e = threadIdx.x; e < 4096; e += blockDim.x) {
    const int r = e >> 6, c = e & 63;  // r = input ch, c = output ch
    float val = 0.f;
    if (center) {
      if (r < 16 && c < 16) {
        val = sc0[r * 16 + c] * 0.25f;
      } else if (r >= 16 && c >= 16) {
        const int u = (r - 16) / 3, i = (r - 16) % 3;
        const int w = (c - 16) / 3, kc = (c - 16) % 3;
        val = (i == kc) ? sc1[u * 16 + w] * 0.25f : 0.f;
      }
    } else {
      if (r < 16 && c < 16) {
        float a = 0.f;
#pragma unroll
        for (int b = 0; b < 4; ++b) a += emb[b] * w000[(b * 16 + r) * 16 + c];
        val = a * INV_NLAT;
      } else if (r < 16) {
        const int w = (c - 16) / 3, kc = (c - 16) % 3;
        float a = 0.f;
#pragma unroll
        for (int b = 0; b < 4; ++b) a += emb[b] * w011[(b * 16 + r) * 16 + w];
        val = a * INV_NLAT * sh[kc];
      } else if (c < 16) {
        const int u = (r - 16) / 3, i = (r - 16) % 3;
        float a = 0.f;
#pragma unroll
        for (int b = 0; b < 4; ++b) a += emb[b] * w110[(b * 16 + u) * 16 + c];
        val = a * INV_NLAT * sh[i] * INV_SQ3;
      } else {
        const int u = (r - 16) / 3, i = (r - 16) % 3;
        const int w = (c - 16) / 3, kc = (c - 16) % 3;
        if (i == kc) {
          float a = 0.f;
#pragma unroll
          for (int b = 0; b < 4; ++b) a += emb[b] * w101[(b * 16 + u) * 16 + w];
          val = a * INV_NLAT;
        }
      }
    }
    // permute into B-fragment layout: B[k = i - ik*32][n = o] per (tap, ik, of)
    const int ik = r >> 5;
    const int lane = ((r >> 3) & 3) * 16 + (c & 15);
    const int of = c >> 4;
    const int j = r & 7;
    g_kb[((size_t)((tap * 2 + ik) * 4 + of) * 64 + lane) * 8 + j] = bf16r(val);
  }
}

// Block: (X, y-group of 4, n). Wave w = y row (y0+w). Out tile: 4y x 48z x 64o.
// Per dx: stage TWO half-slabs (32 ch each, 26624 B) -> 5-6 blocks/CU, no tail.
__global__ __launch_bounds__(256, 5) void conv_mfma(float* __restrict__ out) {
  __shared__ __align__(16) char xs[8 * 52 * 64];  // 8y x 52z x 32i bf16 = 26624 B
  const int t = threadIdx.x;
  const int l = t & 63;
  const int wid = t >> 6;      // wave id = local y
  const int m = l & 15;        // MFMA row/col-within-frag
  const int kq = l >> 4;       // k-quad 0..3
  // bijective XCD swizzle: 1152 blocks = 8 XCDs x 144
  const int bid = blockIdx.x;
  const int wg = (bid & 7) * 144 + (bid >> 3);
  const int X = wg % 48;
  const int yg = (wg / 48) % 12;
  const int n = wg / 576;
  const int y0 = yg << 2;

  float4v acc[3][4];
  const float4v zero4 = {0.f, 0.f, 0.f, 0.f};
#pragma unroll
  for (int zt = 0; zt < 3; ++zt)
#pragma unroll
    for (int of = 0; of < 4; ++of) acc[zt][of] = zero4;

#pragma unroll 1
  for (int dx = 0; dx < 5; ++dx) {
    const unsigned short* gx =
        g_xb + ((size_t)n * PS + (X + dx)) * 173056 + (size_t)y0 * 3328;
#pragma unroll 1
    for (int h = 0; h < 2; ++h) {
      __syncthreads();
      // stage 8y x 52z x 32ch half-slab: 1664 16B-chunks, linear LDS dest,
      // source pre-swizzled (chunk ^= zz&3) to match swizzled read.
#pragma unroll
      for (int s = 0; s < 7; ++s) {
        const int cl = t + (s << 8);
        if (cl < 1664) {
          const int row = cl >> 2, p = cl & 3;
          const int jy = row / 52, zz = row - jy * 52;
          const int sc = p ^ (zz & 3);
          const unsigned short* g = gx + jy * 3328 + zz * 64 + h * 32 + sc * 8;
          char* ldsd = xs + (size_t)((t >> 6) * 64 + (s << 8)) * 16;
          __builtin_amdgcn_global_load_lds(
              (const __attribute__((address_space(1))) unsigned*)g,
              (__attribute__((address_space(3))) unsigned*)ldsd, 16, 0, 0);
        }
      }
      __syncthreads();

#pragma unroll 1
      for (int dy = 0; dy < 5; ++dy) {
        const int rb0 = (wid + dy) * 52 + m;   // slab row (+ zt*16 + dz)
        const int tapb = ((dx * 5 + dy) * 5) * 2 + h;  // (tap*2 + ik) base, ik=h
#pragma unroll
        for (int dz = 0; dz < 5; ++dz) {
          const unsigned short* kbp =
              g_kb + (size_t)(tapb + dz * 2) * 2048 + l * 8;
          const short8 b0 = *(const short8*)(kbp);
          const short8 b1 = *(const short8*)(kbp + 512);
          const short8 b2 = *(const short8*)(kbp + 1024);
          const short8 b3 = *(const short8*)(kbp + 1536);
          short8 a[3];
#pragma unroll
          for (int zt = 0; zt < 3; ++zt) {
            const int row = rb0 + zt * 16 + dz;
            const int byte = row * 64 + ((kq ^ (row & 3)) << 4);
            a[zt] = *(const short8*)(xs + byte);
          }
#pragma unroll
          for (int zt = 0; zt < 3; ++zt) {
            acc[zt][0] = __builtin_amdgcn_mfma_f32_16x16x32_bf16(a[zt], b0, acc[zt][0], 0, 0, 0);
            acc[zt][1] = __builtin_amdgcn_mfma_f32_16x16x32_bf16(a[zt], b1, acc[zt][1], 0, 0, 0);
            acc[zt][2] = __builtin_amdgcn_mfma_f32_16x16x32_bf16(a[zt], b2, acc[zt][2], 0, 0, 0);
            acc[zt][3] = __builtin_amdgcn_mfma_f32_16x16x32_bf16(a[zt], b3, acc[zt][3], 0, 0, 0);
          }
        }
      }
    }
  }

  // C/D layout: col(o) = lane&15, row(z) = (lane>>4)*4 + r   [m89]
  float* op = out + ((((size_t)n * NS + X) * NS + (y0 + wid)) * NS) * NC;
#pragma unroll
  for (int zt = 0; zt < 3; ++zt) {
#pragma unroll
    for (int of = 0; of < 4; ++of) {
#pragma unroll
      for (int r = 0; r < 4; ++r) {
        const int z = zt * 16 + kq * 4 + r;
        const int o = of * 16 + m;
        op[(size_t)z * NC + o] = acc[zt][of][r];
      }
    }
  }
}

extern "C" void kernel_launch(void* const* d_in, const int* in_sizes, int n_in,
                              void* d_out, int out_size, void* d_ws, size_t ws_size,
                              hipStream_t stream) {
  const float* x    = (const float*)d_in[0];
  const float* w000 = (const float*)d_in[1];
  const float* w011 = (const float*)d_in[2];
  const float* w101 = (const float*)d_in[3];
  const float* w110 = (const float*)d_in[4];
  const float* sc0  = (const float*)d_in[5];
  const float* sc1  = (const float*)d_in[6];
  float* out = (float*)d_out;

  pad_cast<<<dim3(52 * 52, 2), 256, 0, stream>>>(x);
  build_kb<<<125, 256, 0, stream>>>(w000, w011, w101, w110, sc0, sc1);
  conv_mfma<<<1152, 256, 0, stream>>>(out);
}

// Round 4
// 251.297 us; speedup vs baseline: 15.8942x; 1.1555x over previous
//
#include <hip/hip_runtime.h>
#include <math.h>

typedef __attribute__((ext_vector_type(8))) short short8;
typedef __attribute__((ext_vector_type(4))) float float4v;

#define NS 48
#define PS 52
#define NC 64

// padded bf16 input: [n][xx 0..51][yy 0..51][zz 0..51][i], borders zero
__device__ __align__(16) unsigned short g_xb[(size_t)2 * PS * PS * PS * NC];
// kernel in MFMA B-fragment layout: [tap 125][ik 2][of 4][lane 64][j 8]
__device__ __align__(16) unsigned short g_kb[125 * 2 * 4 * 64 * 8];

__device__ __forceinline__ unsigned short bf16r(float f) {
  unsigned u = __builtin_bit_cast(unsigned, f);
  u = (u + 0x7FFFu + ((u >> 16) & 1u)) >> 16;
  return (unsigned short)u;
}

__global__ __launch_bounds__(256) void pad_cast(const float* __restrict__ x) {
  const int bx = blockIdx.x;  // xx*52+yy
  const int n = blockIdx.y;
  const int xx = bx / 52, yy = bx % 52;
  const bool inxy = (xx >= 2) && (xx < 50) && (yy >= 2) && (yy < 50);
  unsigned short* dst = g_xb + (((size_t)n * 52 + xx) * 52 + yy) * 3328;
  const float* src = x + ((((size_t)n * 48 + (xx - 2)) * 48 + (yy - 2)) * 48) * 64;
#pragma unroll 1
  for (int tt = threadIdx.x; tt < 832; tt += 256) {
    const int zz = tt >> 4;
    const int i4 = (tt & 15) * 4;
    ushort4 v = make_ushort4(0, 0, 0, 0);
    if (inxy && zz >= 2 && zz < 50) {
      const float4 f = *(const float4*)(src + (size_t)(zz - 2) * 64 + i4);
      v.x = bf16r(f.x); v.y = bf16r(f.y); v.z = bf16r(f.z); v.w = bf16r(f.w);
    }
    *(ushort4*)(dst + (size_t)zz * 64 + i4) = v;
  }
}

__global__ __launch_bounds__(256) void build_kb(
    const float* __restrict__ w000, const float* __restrict__ w011,
    const float* __restrict__ w101, const float* __restrict__ w110,
    const float* __restrict__ sc0,  const float* __restrict__ sc1) {
  const int tap = blockIdx.x;  // 0..124
  const int tz = tap % 5, ty = (tap / 5) % 5, tx = tap / 25;
  const float cx = (float)(tx - 2), cy = (float)(ty - 2), cz = (float)(tz - 2);
  const float norm = sqrtf(cx * cx + cy * cy + cz * cz);
  const float inv = (norm > 0.f) ? (1.f / norm) : 0.f;
  const float SQ3 = 1.7320508075688772f;
  const float sh[3] = {SQ3 * cx * inv, SQ3 * cy * inv, SQ3 * cz * inv};
  float emb[4];
#pragma unroll
  for (int b = 0; b < 4; ++b) {
    const float v = 0.5f * (float)(b + 1);
    const float d = (norm - v) * 2.0f;
    emb[b] = (fabsf(d) < 1.f) ? 1.14136f * expf(2.f - 1.f / (1.f - d * d)) : 0.f;
  }
  const bool center = (tap == 62);
  const float INV_NLAT = 1.0f / 125.0f;
  const float INV_SQ3 = 0.57735026918962576f;
  for (int e = threadIdx.x; e < 4096; e += blockDim.x) {
    const int r = e >> 6, c = e & 63;  // r = input ch, c = output ch
    float val = 0.f;
    if (center) {
      if (r < 16 && c < 16) {
        val = sc0[r * 16 + c] * 0.25f;
      } else if (r >= 16 && c >= 16) {
        const int u = (r - 16) / 3, i = (r - 16) % 3;
        const int w = (c - 16) / 3, kc = (c - 16) % 3;
        val = (i == kc) ? sc1[u * 16 + w] * 0.25f : 0.f;
      }
    } else {
      if (r < 16 && c < 16) {
        float a = 0.f;
#pragma unroll
        for (int b = 0; b < 4; ++b) a += emb[b] * w000[(b * 16 + r) * 16 + c];
        val = a * INV_NLAT;
      } else if (r < 16) {
        const int w = (c - 16) / 3, kc = (c - 16) % 3;
        float a = 0.f;
#pragma unroll
        for (int b = 0; b < 4; ++b) a += emb[b] * w011[(b * 16 + r) * 16 + w];
        val = a * INV_NLAT * sh[kc];
      } else if (c < 16) {
        const int u = (r - 16) / 3, i = (r - 16) % 3;
        float a = 0.f;
#pragma unroll
        for (int b = 0; b < 4; ++b) a += emb[b] * w110[(b * 16 + u) * 16 + c];
        val = a * INV_NLAT * sh[i] * INV_SQ3;
      } else {
        const int u = (r - 16) / 3, i = (r - 16) % 3;
        const int w = (c - 16) / 3, kc = (c - 16) % 3;
        if (i == kc) {
          float a = 0.f;
#pragma unroll
          for (int b = 0; b < 4; ++b) a += emb[b] * w101[(b * 16 + u) * 16 + w];
          val = a * INV_NLAT;
        }
      }
    }
    // permute into B-fragment layout: B[k = i - ik*32][n = o] per (tap, ik, of)
    const int ik = r >> 5;
    const int lane = ((r >> 3) & 3) * 16 + (c & 15);
    const int of = c >> 4;
    const int j = r & 7;
    g_kb[((size_t)((tap * 2 + ik) * 4 + of) * 64 + lane) * 8 + j] = bf16r(val);
  }
}

// Block: 8y x 48z x 64o. 4 waves, wave w owns y rows {y0+2w, y0+2w+1}.
// Slab: 12y-halo x 52z x 32ch (one ik half) = 39936 B, XOR-swizzled (ry>>1)&3.
__global__ __launch_bounds__(256, 3) void conv_mfma(float* __restrict__ out) {
  __shared__ __align__(16) char xs[12 * 52 * 64];  // 39936 B
  const int t = threadIdx.x;
  const int l = t & 63;
  const int wid = t >> 6;
  const int m = l & 15;        // z-within-tile (A) / o-within-frag (C)
  const int kq = l >> 4;       // k-quad 0..3
  // bijective XCD swizzle: 576 blocks = 8 XCDs x 72, X fastest
  const int bid = blockIdx.x;
  const int wg = (bid & 7) * 72 + (bid >> 3);
  const int X = wg % 48;
  const int yg = (wg / 48) % 6;
  const int n = wg / 288;
  const int y0 = yg << 3;

  float4v acc[2][3][4];
  const float4v zero4 = {0.f, 0.f, 0.f, 0.f};
#pragma unroll
  for (int y = 0; y < 2; ++y)
#pragma unroll
    for (int zt = 0; zt < 3; ++zt)
#pragma unroll
      for (int of = 0; of < 4; ++of) acc[y][zt][of] = zero4;

#pragma unroll 1
  for (int dx = 0; dx < 5; ++dx) {
    const unsigned short* gx =
        g_xb + ((size_t)n * PS + (X + dx)) * 173056 + (size_t)y0 * 3328;
#pragma unroll 1
    for (int h = 0; h < 2; ++h) {
      __syncthreads();
      // stage 12y x 52z x 32ch half-slab: 2496 16B-chunks, linear LDS dest,
      // source pre-swizzled (chunk ^= (ry>>1)&3) to match swizzled read.
#pragma unroll
      for (int s = 0; s < 10; ++s) {
        const int cl = t + (s << 8);
        if (cl < 2496) {
          const int ry = cl >> 2, p = cl & 3;
          const int jy = ry / 52, zz = ry - jy * 52;
          const int sc = p ^ ((ry >> 1) & 3);
          const unsigned short* g = gx + jy * 3328 + zz * 64 + h * 32 + sc * 8;
          char* ldsd = xs + (size_t)((t >> 6) * 64 + (s << 8)) * 16;
          __builtin_amdgcn_global_load_lds(
              (const __attribute__((address_space(1))) unsigned*)g,
              (__attribute__((address_space(3))) unsigned*)ldsd, 16, 0, 0);
        }
      }
      __syncthreads();

#pragma unroll 1
      for (int dy = 0; dy < 5; ++dy) {
        const int rbase = (2 * wid + dy) * 52 + m;     // slab row for y=0
        const int tapb = ((dx * 5 + dy) * 5) * 2 + h;  // (tap*2 + ik), ik=h
#pragma unroll
        for (int dz = 0; dz < 5; ++dz) {
          const unsigned short* kbp =
              g_kb + (size_t)(tapb + dz * 2) * 2048 + l * 8;
          const short8 b0 = *(const short8*)(kbp);
          const short8 b1 = *(const short8*)(kbp + 512);
          const short8 b2 = *(const short8*)(kbp + 1024);
          const short8 b3 = *(const short8*)(kbp + 1536);
          short8 a[2][3];
#pragma unroll
          for (int y = 0; y < 2; ++y) {
#pragma unroll
            for (int zt = 0; zt < 3; ++zt) {
              const int ry = rbase + y * 52 + zt * 16 + dz;
              const int byte = ry * 64 + ((kq ^ ((ry >> 1) & 3)) << 4);
              a[y][zt] = *(const short8*)(xs + byte);
            }
          }
#pragma unroll
          for (int y = 0; y < 2; ++y) {
#pragma unroll
            for (int zt = 0; zt < 3; ++zt) {
              acc[y][zt][0] = __builtin_amdgcn_mfma_f32_16x16x32_bf16(a[y][zt], b0, acc[y][zt][0], 0, 0, 0);
              acc[y][zt][1] = __builtin_amdgcn_mfma_f32_16x16x32_bf16(a[y][zt], b1, acc[y][zt][1], 0, 0, 0);
              acc[y][zt][2] = __builtin_amdgcn_mfma_f32_16x16x32_bf16(a[y][zt], b2, acc[y][zt][2], 0, 0, 0);
              acc[y][zt][3] = __builtin_amdgcn_mfma_f32_16x16x32_bf16(a[y][zt], b3, acc[y][zt][3], 0, 0, 0);
            }
          }
        }
      }
    }
  }

  // C/D layout: col(o) = lane&15, row(z) = (lane>>4)*4 + r   [m89]
#pragma unroll
  for (int y = 0; y < 2; ++y) {
    float* op = out +
        ((((size_t)n * NS + X) * NS + (y0 + 2 * wid + y)) * NS) * NC;
#pragma unroll
    for (int zt = 0; zt < 3; ++zt) {
#pragma unroll
      for (int of = 0; of < 4; ++of) {
#pragma unroll
        for (int r = 0; r < 4; ++r) {
          const int z = zt * 16 + kq * 4 + r;
          const int o = of * 16 + m;
          op[(size_t)z * NC + o] = acc[y][zt][of][r];
        }
      }
    }
  }
}

extern "C" void kernel_launch(void* const* d_in, const int* in_sizes, int n_in,
                              void* d_out, int out_size, void* d_ws, size_t ws_size,
                              hipStream_t stream) {
  const float* x    = (const float*)d_in[0];
  const float* w000 = (const float*)d_in[1];
  const float* w011 = (const float*)d_in[2];
  const float* w101 = (const float*)d_in[3];
  const float* w110 = (const float*)d_in[4];
  const float* sc0  = (const float*)d_in[5];
  const float* sc1  = (const float*)d_in[6];
  float* out = (float*)d_out;

  pad_cast<<<dim3(52 * 52, 2), 256, 0, stream>>>(x);
  build_kb<<<125, 256, 0, stream>>>(w000, w011, w101, w110, sc0, sc1);
  conv_mfma<<<576, 256, 0, stream>>>(out);
}